// Round 6
// baseline (406.027 us; speedup 1.0000x reference)
//
#include <hip/hip_runtime.h>

#define SLEN  512
#define BATCH 256
#define NTAGS 128
#define NTHR  1024   // j = tid>>3 (0..127), h = tid&7 -> 16 waves, 4/SIMD

// quad_perm DPP within a quad (pure VALU)
__device__ __forceinline__ int dpp_qperm_b1(int x) {  // lane <- lane^1
    return __builtin_amdgcn_update_dpp(0, x, 0xB1, 0xF, 0xF, true);
}
__device__ __forceinline__ int dpp_qperm_4e(int x) {  // lane <- lane^2
    return __builtin_amdgcn_update_dpp(0, x, 0x4E, 0xF, 0xF, true);
}
// lane <- lane^4 (BitMode swizzle: xor=4, and=0x1F)
__device__ __forceinline__ int swz_xor4(int x) {
    return __builtin_amdgcn_ds_swizzle(x, 0x101F);
}

// Value+index pair; b must carry the HIGHER index range:
// strict > keeps the first (lower-index) maximum -> np.argmax tie rule.
struct VI { float v; int i; };
__device__ __forceinline__ VI vmax2(VI a, VI b) { return (b.v > a.v) ? b : a; }

__global__ __launch_bounds__(NTHR, 4) void viterbi_kernel(
    const float* __restrict__ em,      // [S,B,T]
    const int*   __restrict__ mask,    // [S,B]
    const float* __restrict__ start_t, // [T]
    const float* __restrict__ end_t,   // [T]
    const float* __restrict__ trans,   // [T,T]
    float* __restrict__ out)           // [B*S] tags (as float), then [B] scores
{
    const int b    = blockIdx.x;
    const int tid  = threadIdx.x;
    const int j    = tid >> 3;         // 0..127
    const int h    = tid & 7;          // 0..7
    const int base = h << 4;           // h*16
    const bool writer = (h == 0);
    const int jslot = j + (j >> 4) * 4;   // chunk j>>4 at float offset (j>>4)*20

    // sc double-buffer; chunk h at float offset h*20 -> the 8 distinct b128
    // addresses of a wave-read cover all 32 banks (conflict-free, full width)
    __shared__ __align__(16) float scbuf[2][8 * 20];
    __shared__ float fin[NTAGS];
    __shared__ int   maskv[SLEN];
    __shared__ unsigned char hist[SLEN - 1][NTAGS];   // 65408 B
    __shared__ unsigned char exitc[8][NTAGS];
    __shared__ unsigned char st_tags[8];
    __shared__ unsigned char tagseq[SLEN];
    __shared__ float bestval_s;
    __shared__ int   bestj_s;

    // ---- 16 NAMED transition-column registers: trans[base+k][j] ----
    const float* trp = trans + (size_t)base * NTAGS + j;
    const float t00 = trp[ 0*NTAGS], t01 = trp[ 1*NTAGS], t02 = trp[ 2*NTAGS], t03 = trp[ 3*NTAGS];
    const float t04 = trp[ 4*NTAGS], t05 = trp[ 5*NTAGS], t06 = trp[ 6*NTAGS], t07 = trp[ 7*NTAGS];
    const float t08 = trp[ 8*NTAGS], t09 = trp[ 9*NTAGS], t10 = trp[10*NTAGS], t11 = trp[11*NTAGS];
    const float t12 = trp[12*NTAGS], t13 = trp[13*NTAGS], t14 = trp[14*NTAGS], t15 = trp[15*NTAGS];

    if (tid < SLEN)
        maskv[tid] = mask[tid * BATCH + b];

    float scj = 0.f;
    if (writer) {
        scj = start_t[j] + em[(size_t)b * NTAGS + j];   // exact ref associativity
        scbuf[0][jslot] = scj;
    }
    __syncthreads();

    const float* emp = em + (size_t)BATCH * NTAGS + (size_t)b * NTAGS + j; // t=1
    float em_next = *emp;

    int p = 0;
    for (int t = 1; t < SLEN; ++t) {
        const float em_cur = em_next;
        if (t + 1 < SLEN) { emp += BATCH * NTAGS; em_next = *emp; }

        // 4 named float4 broadcast reads of this thread's 16-float sc chunk
        const float4* sq = (const float4*)&scbuf[p][h * 20];   // h*80 B, 16B-aligned
        const float4 q0 = sq[0], q1 = sq[1], q2 = sq[2], q3 = sq[3];

        // 16 candidates: c_k = fl(fl(sc[base+k] + trans[base+k][j]) + em) — exact ref order
        const float c00 = (q0.x + t00) + em_cur, c01 = (q0.y + t01) + em_cur;
        const float c02 = (q0.z + t02) + em_cur, c03 = (q0.w + t03) + em_cur;
        const float c04 = (q1.x + t04) + em_cur, c05 = (q1.y + t05) + em_cur;
        const float c06 = (q1.z + t06) + em_cur, c07 = (q1.w + t07) + em_cur;
        const float c08 = (q2.x + t08) + em_cur, c09 = (q2.y + t09) + em_cur;
        const float c10 = (q2.z + t10) + em_cur, c11 = (q2.w + t11) + em_cur;
        const float c12 = (q3.x + t12) + em_cur, c13 = (q3.y + t13) + em_cur;
        const float c14 = (q3.z + t14) + em_cur, c15 = (q3.w + t15) + em_cur;

        // Adjacent-pair tree, all named: strict > at every level == first-occurrence
        const VI m0 = vmax2(VI{c00, 0}, VI{c01, 1}),  m1 = vmax2(VI{c02, 2}, VI{c03, 3});
        const VI m2 = vmax2(VI{c04, 4}, VI{c05, 5}),  m3 = vmax2(VI{c06, 6}, VI{c07, 7});
        const VI m4 = vmax2(VI{c08, 8}, VI{c09, 9}),  m5 = vmax2(VI{c10,10}, VI{c11,11});
        const VI m6 = vmax2(VI{c12,12}, VI{c13,13}),  m7 = vmax2(VI{c14,14}, VI{c15,15});
        const VI n0 = vmax2(m0, m1), n1 = vmax2(m2, m3);
        const VI n2 = vmax2(m4, m5), n3 = vmax2(m6, m7);
        const VI o0 = vmax2(n0, n1), o1 = vmax2(n2, n3);
        const VI r  = vmax2(o0, o1);

        // 3-stage butterfly over h. From lane h==0's view every partner holds a
        // HIGHER i-base, so strict > keeps the first max (only h==0 is consumed;
        // intermediate correctness holds for the even-lane path: validated r3/r5).
        float v  = r.v;
        int   gi = base + r.i;
        {
            float vo = __int_as_float(dpp_qperm_b1(__float_as_int(v)));
            int   io = dpp_qperm_b1(gi);
            if (vo > v) { v = vo; gi = io; }
        }
        {
            float vo = __int_as_float(dpp_qperm_4e(__float_as_int(v)));
            int   io = dpp_qperm_4e(gi);
            if (vo > v) { v = vo; gi = io; }
        }
        {
            float vo = __int_as_float(swz_xor4(__float_as_int(v)));
            int   io = swz_xor4(gi);
            if (vo > v) { v = vo; gi = io; }
        }

        if (writer) {
            hist[t - 1][j] = (unsigned char)gi;   // recorded unconditionally (ref does too)
            scj = maskv[t] ? v : scj;             // where(mask, next, old), register-carried
            scbuf[p ^ 1][jslot] = scj;
        }
        __syncthreads();                           // ONE barrier per step
        p ^= 1;
    }

    // final = sc + end_transitions, straight from writer registers
    if (writer) fin[j] = scj + end_t[j];
    __syncthreads();

    // first-occurrence argmax over 128 tags (wave 0)
    if (tid < 64) {
        float v  = fin[tid]; int bj = tid;
        float v1 = fin[tid + 64];
        if (v1 > v) { v = v1; bj = tid + 64; }
#pragma unroll
        for (int off = 32; off > 0; off >>= 1) {
            float ov = __shfl_xor(v, off, 64);
            int   oj = __shfl_xor(bj, off, 64);
            if (ov > v || (ov == v && oj < bj)) { v = ov; bj = oj; }
        }
        if (tid == 0) { bestval_s = v; bestj_s = bj; }
    }
    __syncthreads();

    // ---- Chunked parallel backtrace: 8 chunks x 128 tags = 1 chain/thread ----
    {
        const int k = tid & 127;
        const int c = tid >> 7;        // 0..7
        int tag = k;
        for (int u = 63; u >= 0; --u) {
            const int s = c * 64 + u;
            if (s <= SLEN - 2) {
                int pv = hist[s][tag];
                tag = maskv[s + 1] ? pv : tag;
            }
        }
        exitc[c][k] = (unsigned char)tag;
    }
    __syncthreads();

    if (tid == 0) {
        int tag = bestj_s;
        for (int c = 7; c >= 0; --c) {
            st_tags[c] = (unsigned char)tag;
            tag = exitc[c][tag];
        }
        out[BATCH * SLEN + b] = bestval_s;        // best_path_score
    }
    __syncthreads();

    if (tid < 8) {
        const int c = tid;
        int tag = st_tags[c];
        if (c == 7) tagseq[SLEN - 1] = (unsigned char)tag;
        const int shi = (c == 7) ? (SLEN - 2) : (c * 64 + 63);
        for (int s = shi; s >= c * 64; --s) {
            int pv = hist[s][tag];
            tag = maskv[s + 1] ? pv : tag;
            tagseq[s] = (unsigned char)tag;
        }
    }
    __syncthreads();

    // Coalesced tag writeout as float: out0 is tags.T -> [B, S] row-major
    if (tid < SLEN)
        out[b * SLEN + tid] = (float)tagseq[tid];
}

extern "C" void kernel_launch(void* const* d_in, const int* in_sizes, int n_in,
                              void* d_out, int out_size, void* d_ws, size_t ws_size,
                              hipStream_t stream) {
    const float* em      = (const float*)d_in[0];
    const int*   mask    = (const int*)d_in[1];
    const float* start_t = (const float*)d_in[2];
    const float* end_t   = (const float*)d_in[3];
    const float* trans   = (const float*)d_in[4];
    float* out = (float*)d_out;

    viterbi_kernel<<<dim3(BATCH), dim3(NTHR), 0, stream>>>(
        em, mask, start_t, end_t, trans, out);
}

// Round 7
// 398.433 us; speedup vs baseline: 1.0191x; 1.0191x over previous
//
#include <hip/hip_runtime.h>

#define SLEN  512
#define BATCH 256
#define NTAGS 128
#define NTHR  1024   // j = tid>>3 (0..127), h = tid&7 -> 16 waves, 4/SIMD

__device__ __forceinline__ int dpp_qperm_b1(int x) {  // lane <- lane^1
    return __builtin_amdgcn_update_dpp(0, x, 0xB1, 0xF, 0xF, true);
}
__device__ __forceinline__ int dpp_qperm_4e(int x) {  // lane <- lane^2
    return __builtin_amdgcn_update_dpp(0, x, 0x4E, 0xF, 0xF, true);
}
__device__ __forceinline__ int swz_xor4(int x) {      // lane <- lane^4 (validated r6)
    return __builtin_amdgcn_ds_swizzle(x, 0x101F);
}

// Value+index pair; b must carry the HIGHER index range:
// strict > keeps the first (lower-index) maximum -> np.argmax tie rule.
struct VI { float v; int i; };
__device__ __forceinline__ VI vmax2(VI a, VI b) { return (b.v > a.v) ? b : a; }

// One forward step. USE_MASK=0 is the all-valid fast path (no maskv read).
#define VIT_STEP(USE_MASK)                                                     \
  {                                                                            \
    const float em_cur = em_next;                                              \
    if (t + 1 < SLEN) { emp += BATCH * NTAGS; em_next = *emp; }                \
    const float4* sq = (const float4*)&scbuf[p][h * 20];                       \
    const float4 q0 = sq[0], q1 = sq[1], q2 = sq[2], q3 = sq[3];               \
    const float c00 = (q0.x + t00) + em_cur, c01 = (q0.y + t01) + em_cur;      \
    const float c02 = (q0.z + t02) + em_cur, c03 = (q0.w + t03) + em_cur;      \
    const float c04 = (q1.x + t04) + em_cur, c05 = (q1.y + t05) + em_cur;      \
    const float c06 = (q1.z + t06) + em_cur, c07 = (q1.w + t07) + em_cur;      \
    const float c08 = (q2.x + t08) + em_cur, c09 = (q2.y + t09) + em_cur;      \
    const float c10 = (q2.z + t10) + em_cur, c11 = (q2.w + t11) + em_cur;      \
    const float c12 = (q3.x + t12) + em_cur, c13 = (q3.y + t13) + em_cur;      \
    const float c14 = (q3.z + t14) + em_cur, c15 = (q3.w + t15) + em_cur;      \
    const VI m0 = vmax2(VI{c00, 0}, VI{c01, 1}),  m1 = vmax2(VI{c02, 2}, VI{c03, 3}); \
    const VI m2 = vmax2(VI{c04, 4}, VI{c05, 5}),  m3 = vmax2(VI{c06, 6}, VI{c07, 7}); \
    const VI m4 = vmax2(VI{c08, 8}, VI{c09, 9}),  m5 = vmax2(VI{c10,10}, VI{c11,11}); \
    const VI m6 = vmax2(VI{c12,12}, VI{c13,13}),  m7 = vmax2(VI{c14,14}, VI{c15,15}); \
    const VI n0 = vmax2(m0, m1), n1 = vmax2(m2, m3);                           \
    const VI n2 = vmax2(m4, m5), n3 = vmax2(m6, m7);                           \
    const VI o0 = vmax2(n0, n1), o1 = vmax2(n2, n3);                           \
    const VI r  = vmax2(o0, o1);                                               \
    float v  = r.v;                                                            \
    int   gi = base + r.i;                                                     \
    {                                                                          \
      float vo = __int_as_float(dpp_qperm_b1(__float_as_int(v)));              \
      int   io = dpp_qperm_b1(gi);                                             \
      if (vo > v) { v = vo; gi = io; }                                         \
    }                                                                          \
    {                                                                          \
      float vo = __int_as_float(dpp_qperm_4e(__float_as_int(v)));              \
      int   io = dpp_qperm_4e(gi);                                             \
      if (vo > v) { v = vo; gi = io; }                                         \
    }                                                                          \
    {                                                                          \
      float vo = __int_as_float(swz_xor4(__float_as_int(v)));                  \
      int   io = swz_xor4(gi);                                                 \
      if (vo > v) { v = vo; gi = io; }                                         \
    }                                                                          \
    if (writer) {                                                              \
      hist[t - 1][j] = (unsigned char)gi;                                      \
      if (USE_MASK) { scj = maskv[t] ? v : scj; } else { scj = v; }            \
      scbuf[p ^ 1][jslot] = scj;                                               \
    }                                                                          \
    /* LDS-visibility barrier WITHOUT vmcnt drain: em prefetch stays in flight */ \
    asm volatile("s_waitcnt lgkmcnt(0)\n\ts_barrier" ::: "memory");            \
    p ^= 1;                                                                    \
  }

__global__ __launch_bounds__(NTHR, 4) void viterbi_kernel(
    const float* __restrict__ em,      // [S,B,T]
    const int*   __restrict__ mask,    // [S,B]
    const float* __restrict__ start_t, // [T]
    const float* __restrict__ end_t,   // [T]
    const float* __restrict__ trans,   // [T,T]
    float* __restrict__ out)           // [B*S] tags (as float), then [B] scores
{
    const int b    = blockIdx.x;
    const int tid  = threadIdx.x;
    const int j    = tid >> 3;         // 0..127
    const int h    = tid & 7;          // 0..7
    const int base = h << 4;           // h*16
    const bool writer = (h == 0);
    const int jslot = j + (j >> 4) * 4;   // chunk j>>4 at float offset (j>>4)*20

    __shared__ __align__(16) float scbuf[2][8 * 20];
    __shared__ float fin[NTAGS];
    __shared__ int   maskv[SLEN];
    __shared__ int   allv_s;
    __shared__ unsigned char hist[SLEN - 1][NTAGS];   // 65408 B
    __shared__ unsigned char exitc[8][NTAGS];
    __shared__ unsigned char st_tags[8];
    __shared__ unsigned char tagseq[SLEN];
    __shared__ float bestval_s;
    __shared__ int   bestj_s;

    // ---- 16 NAMED transition-column registers: trans[base+k][j] ----
    const float* trp = trans + (size_t)base * NTAGS + j;
    float t00 = trp[ 0*NTAGS], t01 = trp[ 1*NTAGS], t02 = trp[ 2*NTAGS], t03 = trp[ 3*NTAGS];
    float t04 = trp[ 4*NTAGS], t05 = trp[ 5*NTAGS], t06 = trp[ 6*NTAGS], t07 = trp[ 7*NTAGS];
    float t08 = trp[ 8*NTAGS], t09 = trp[ 9*NTAGS], t10 = trp[10*NTAGS], t11 = trp[11*NTAGS];
    float t12 = trp[12*NTAGS], t13 = trp[13*NTAGS], t14 = trp[14*NTAGS], t15 = trp[15*NTAGS];
    // PIN in VGPRs: the asm becomes the defining op -> compiler cannot
    // rematerialize these via per-iteration global reloads (r6: VGPR=28 proved it did).
    asm volatile("" : "+v"(t00), "+v"(t01), "+v"(t02), "+v"(t03),
                      "+v"(t04), "+v"(t05), "+v"(t06), "+v"(t07),
                      "+v"(t08), "+v"(t09), "+v"(t10), "+v"(t11),
                      "+v"(t12), "+v"(t13), "+v"(t14), "+v"(t15));

    if (tid == 0) allv_s = 1;
    int mv = 1;
    if (tid < SLEN) {
        mv = mask[tid * BATCH + b];
        maskv[tid] = mv;
    }
    __syncthreads();
    if (mv == 0) allv_s = 0;   // benign race: all writers store 0

    float scj = 0.f;
    if (writer) {
        scj = start_t[j] + em[(size_t)b * NTAGS + j];   // exact ref associativity
        scbuf[0][jslot] = scj;
    }
    __syncthreads();
    const int allv = allv_s;

    const float* emp = em + (size_t)BATCH * NTAGS + (size_t)b * NTAGS + j; // t=1
    float em_next = *emp;

    int p = 0;
    if (allv) {
        for (int t = 1; t < SLEN; ++t) VIT_STEP(0)
    } else {
        for (int t = 1; t < SLEN; ++t) VIT_STEP(1)
    }

    // final = sc + end_transitions, straight from writer registers
    if (writer) fin[j] = scj + end_t[j];
    __syncthreads();

    // first-occurrence argmax over 128 tags (wave 0)
    if (tid < 64) {
        float v  = fin[tid]; int bj = tid;
        float v1 = fin[tid + 64];
        if (v1 > v) { v = v1; bj = tid + 64; }
#pragma unroll
        for (int off = 32; off > 0; off >>= 1) {
            float ov = __shfl_xor(v, off, 64);
            int   oj = __shfl_xor(bj, off, 64);
            if (ov > v || (ov == v && oj < bj)) { v = ov; bj = oj; }
        }
        if (tid == 0) { bestval_s = v; bestj_s = bj; }
    }
    __syncthreads();

    // ---- Chunked parallel backtrace: 8 chunks x 128 tags = 1 chain/thread ----
    {
        const int k = tid & 127;
        const int c = tid >> 7;        // 0..7
        int tag = k;
        for (int u = 63; u >= 0; --u) {
            const int s = c * 64 + u;
            if (s <= SLEN - 2) {
                int pv = hist[s][tag];
                tag = maskv[s + 1] ? pv : tag;
            }
        }
        exitc[c][k] = (unsigned char)tag;
    }
    __syncthreads();

    if (tid == 0) {
        int tag = bestj_s;
        for (int c = 7; c >= 0; --c) {
            st_tags[c] = (unsigned char)tag;
            tag = exitc[c][tag];
        }
        out[BATCH * SLEN + b] = bestval_s;        // best_path_score
    }
    __syncthreads();

    if (tid < 8) {
        const int c = tid;
        int tag = st_tags[c];
        if (c == 7) tagseq[SLEN - 1] = (unsigned char)tag;
        const int shi = (c == 7) ? (SLEN - 2) : (c * 64 + 63);
        for (int s = shi; s >= c * 64; --s) {
            int pv = hist[s][tag];
            tag = maskv[s + 1] ? pv : tag;
            tagseq[s] = (unsigned char)tag;
        }
    }
    __syncthreads();

    // Coalesced tag writeout as float: out0 is tags.T -> [B, S] row-major
    if (tid < SLEN)
        out[b * SLEN + tid] = (float)tagseq[tid];
}

extern "C" void kernel_launch(void* const* d_in, const int* in_sizes, int n_in,
                              void* d_out, int out_size, void* d_ws, size_t ws_size,
                              hipStream_t stream) {
    const float* em      = (const float*)d_in[0];
    const int*   mask    = (const int*)d_in[1];
    const float* start_t = (const float*)d_in[2];
    const float* end_t   = (const float*)d_in[3];
    const float* trans   = (const float*)d_in[4];
    float* out = (float*)d_out;

    viterbi_kernel<<<dim3(BATCH), dim3(NTHR), 0, stream>>>(
        em, mask, start_t, end_t, trans, out);
}